// Round 8
// baseline (91.816 us; speedup 1.0000x reference)
//
#include <hip/hip_runtime.h>
#include <math.h>

#define NN   8192
#define DD   128
#define CLS  16
#define ALPHA 0.2f
#define CAP  256        // per-row neighbor capacity (deg ~33 +- 5.7; 256 = 40 sigma)
#define SCAN_BLOCKS 2048
#define SCAN_THREADS (SCAN_BLOCKS * 256)   // 524288 -> fully resident grid

typedef unsigned int uv4 __attribute__((ext_vector_type(4)));

// ---------------------------------------------------------------------------
// Kernel 1: per-row feature transform (verified r2-r7) + encoding probe
// (block 0) + cnt zeroing (4 ints per block; 2048 blocks cover NN).
//   h[i] = (artanh(||x_i||)/||x_i||) * x_i @ W + b ; s=h.a_src ; dv=h.a_dst
// ---------------------------------------------------------------------------
__global__ __launch_bounds__(256) void hat_feat(
    const float* __restrict__ x, const float* __restrict__ W,
    const float* __restrict__ b, const float* __restrict__ a_src,
    const float* __restrict__ a_dst, const unsigned char* __restrict__ adj,
    float* __restrict__ h, float* __restrict__ s, float* __restrict__ dv,
    int* __restrict__ flag, int* __restrict__ cnt)
{
    const int lane = threadIdx.x & 63;
    const int row  = (blockIdx.x << 2) + (threadIdx.x >> 6);

    // zero the per-row atomic counters for this replay (stream-ordered
    // before hat_scan, so no race)
    if (threadIdx.x < 4) cnt[(blockIdx.x << 2) + threadIdx.x] = 0;

    // encoding probe: byte-bool vs int32 0/1 (see r2 analysis)
    if (blockIdx.x == 0 && threadIdx.x < 64) {
        const int i = threadIdx.x + 1;
        const int ok = ((i & 3) != 0) && (adj[(size_t)i * (NN + 1)] != 0);
        unsigned long long bb = __ballot(ok);
        if (threadIdx.x == 0) *flag = (__popcll(bb) > 24) ? 1 : 0;
    }

    const float* xr = x + (size_t)row * DD;
    float x0 = xr[lane];
    float x1 = xr[lane + 64];

    float nsq = x0 * x0 + x1 * x1;
    #pragma unroll
    for (int o = 32; o > 0; o >>= 1) nsq += __shfl_xor(nsq, o);

    float norm = fmaxf(sqrtf(nsq), 1e-15f);
    float t    = fminf(norm, 1.0f - 1e-7f);
    float art  = 0.5f * (log1pf(t) - log1pf(-t));
    float scl  = art / norm;
    x0 *= scl;
    x1 *= scl;

    float hc[CLS];
    #pragma unroll
    for (int c = 0; c < CLS; ++c)
        hc[c] = x0 * W[lane * CLS + c] + x1 * W[(lane + 64) * CLS + c];

    #pragma unroll
    for (int o = 32; o > 0; o >>= 1) {
        #pragma unroll
        for (int c = 0; c < CLS; ++c) hc[c] += __shfl_xor(hc[c], o);
    }

    float sv = 0.0f, dvv = 0.0f;
    #pragma unroll
    for (int c = 0; c < CLS; ++c) {
        hc[c] += b[c];
        sv  += hc[c] * a_src[c];
        dvv += hc[c] * a_dst[c];
    }

    if (lane == 0) {
        float* hr = h + (size_t)row * CLS;
        #pragma unroll
        for (int c = 0; c < CLS; ++c) hr[c] = hc[c];
        s[row]  = sv;
        dv[row] = dvv;
    }
}

// ---------------------------------------------------------------------------
// Kernel 2: copy-shaped adjacency scan. Fully-resident grid (2048 x 256),
// flat grid-stride over uint4: every iteration the grid sweeps one dense
// 8 MB window in order (per-channel sequential, like the fill/copy kernels
// that sustain ~7 TB/s). Hot path per 16 B: or3 + cmp + branch. Rare hits
// (~0.4%) appended to per-row lists via atomicAdd (set deterministic;
// order only perturbs float reassociation ~1e-6 << threshold).
// ---------------------------------------------------------------------------
__global__ __launch_bounds__(256) void hat_scan(
    const unsigned char* __restrict__ adj, const int* __restrict__ flag,
    int* __restrict__ nbr, int* __restrict__ cnt)
{
    const int tid = blockIdx.x * 256 + threadIdx.x;
    const uv4* base = reinterpret_cast<const uv4*>(adj);

    if (*flag == 0) {
        // int32 0/1: NN*NN dwords = 16777216 uint4s, 32 sweeps
        #pragma unroll 4
        for (int k = 0; k < 32; ++k) {
            const int u = k * SCAN_THREADS + tid;
            const uv4 a = base[u];
            if ((a[0] | a[1] | a[2] | a[3]) != 0u) {
                const int row = u >> 11;            // 2048 uint4 per row
                const int c0  = (u & 2047) << 2;
                #pragma unroll
                for (int d = 0; d < 4; ++d)
                    if (a[d] != 0u) {
                        const int pos = atomicAdd(&cnt[row], 1);
                        if (pos < CAP) nbr[row * CAP + pos] = c0 + d;
                    }
            }
        }
    } else {
        // byte-bool: NN*NN bytes = 4194304 uint4s, 8 sweeps
        #pragma unroll 4
        for (int k = 0; k < 8; ++k) {
            const int u = k * SCAN_THREADS + tid;
            const uv4 a = base[u];
            if ((a[0] | a[1] | a[2] | a[3]) != 0u) {
                const int row = u >> 9;             // 512 uint4 per row
                const int c0  = (u & 511) << 4;
                #pragma unroll
                for (int d = 0; d < 4; ++d) {
                    const unsigned v = a[d];
                    if (v != 0u) {
                        #pragma unroll
                        for (int bb = 0; bb < 4; ++bb)
                            if ((v >> (bb * 8)) & 0xffu) {
                                const int pos = atomicAdd(&cnt[row], 1);
                                if (pos < CAP) nbr[row * CAP + pos] = c0 + (d << 2) + bb;
                            }
                    }
                }
            }
        }
    }
}

// ---------------------------------------------------------------------------
// Kernel 3: softmax-aggregate over per-row lists (L2-hot). One wave per row.
// Pass 1: lane-parallel max (order-independent). Pass 2: 4-hit-parallel
// channel-split accumulate (group g takes hit base+g, lane owns channel
// cc=lane&15). Verified epilogue: elu -> expmap0 -> proj.
// ---------------------------------------------------------------------------
__global__ __launch_bounds__(256) void hat_agg(
    const float* __restrict__ h, const float* __restrict__ s,
    const float* __restrict__ dv, const int* __restrict__ nbr,
    const int* __restrict__ cnt, float* __restrict__ out)
{
    const int lane = threadIdx.x & 63;
    const int row  = (blockIdx.x << 2) + (threadIdx.x >> 6);
    const int cc   = lane & 15;
    const int g    = lane >> 4;

    const float si = s[row];
    int n = cnt[row];
    n = (n < CAP) ? n : CAP;
    const int* rb = nbr + (size_t)row * CAP;

    float mx = -3.0e38f;
    for (int i = lane; i < n; i += 64) {
        float e = si + dv[rb[i]];
        e = (e > 0.0f) ? e : ALPHA * e;
        mx = fmaxf(mx, e);
    }
    #pragma unroll
    for (int o = 32; o > 0; o >>= 1) mx = fmaxf(mx, __shfl_xor(mx, o));

    float l = 0.0f, acc = 0.0f;
    for (int base = 0; base < n; base += 4) {
        const int idx = base + g;
        if (idx < n) {
            const int j = rb[idx];
            float e = si + dv[j];
            e = (e > 0.0f) ? e : ALPHA * e;
            const float w = __expf(e - mx);
            l += w;
            acc = fmaf(w, h[(size_t)j * CLS + cc], acc);
        }
    }
    l   += __shfl_xor(l, 16);   l   += __shfl_xor(l, 32);
    acc += __shfl_xor(acc, 16); acc += __shfl_xor(acc, 32);

    float* orow = out + (size_t)row * CLS;
    if (l > 0.0f) {
        float u = acc / l;
        u = (u > 0.0f) ? u : expm1f(u);
        float nsq = u * u;
        #pragma unroll
        for (int o = 8; o > 0; o >>= 1) nsq += __shfl_xor(nsq, o);
        float norm = fmaxf(sqrtf(nsq), 1e-15f);
        float th   = tanhf(norm);
        float sc2  = th / norm;
        const float maxnorm = 1.0f - 1e-5f;
        float sc3  = (th > maxnorm) ? (maxnorm / th) : 1.0f;
        if (lane < CLS) orow[lane] = u * sc2 * sc3;
    } else {
        if (lane < CLS) orow[lane] = 0.0f;
    }
}

// ---------------------------------------------------------------------------
extern "C" void kernel_launch(void* const* d_in, const int* in_sizes, int n_in,
                              void* d_out, int out_size, void* d_ws, size_t ws_size,
                              hipStream_t stream) {
    const float*         x     = (const float*)d_in[0];
    const unsigned char* adj   = (const unsigned char*)d_in[1];
    const float*         W     = (const float*)d_in[2];
    const float*         b     = (const float*)d_in[3];
    const float*         a_src = (const float*)d_in[4];
    const float*         a_dst = (const float*)d_in[5];
    float*               out   = (float*)d_out;

    float* h    = (float*)d_ws;                    // [NN, CLS]
    float* s    = h + (size_t)NN * CLS;            // [NN]
    float* dv   = s + NN;                          // [NN]
    int*   flag = (int*)(dv + NN);                 // [1]
    int*   cnt  = flag + 1;                        // [NN]
    int*   nbr  = cnt + NN;                        // [NN, CAP]

    hat_feat<<<NN / 4,      256, 0, stream>>>(x, W, b, a_src, a_dst, adj,
                                              h, s, dv, flag, cnt);
    hat_scan<<<SCAN_BLOCKS, 256, 0, stream>>>(adj, flag, nbr, cnt);
    hat_agg <<<NN / 4,      256, 0, stream>>>(h, s, dv, nbr, cnt, out);
}

// Round 9
// 58.598 us; speedup vs baseline: 1.5669x; 1.5669x over previous
//
#include <hip/hip_runtime.h>
#include <math.h>

#define NN   8192
#define DD   128
#define CLS  16
#define ALPHA 0.2f
#define QCAP 128        // per-quarter-row LDS hit capacity (expected ~8, 45 sigma)

typedef unsigned int uv4 __attribute__((ext_vector_type(4)));

// ---------------------------------------------------------------------------
// Kernel 1: per-row feature transform (verified r2-r8) + encoding probe.
//   h[i] = (artanh(||x_i||)/||x_i||) * x_i @ W + b ; s=h.a_src ; dv=h.a_dst
// ---------------------------------------------------------------------------
__global__ __launch_bounds__(256) void hat_feat(
    const float* __restrict__ x, const float* __restrict__ W,
    const float* __restrict__ b, const float* __restrict__ a_src,
    const float* __restrict__ a_dst, const unsigned char* __restrict__ adj,
    float* __restrict__ h, float* __restrict__ s, float* __restrict__ dv,
    int* __restrict__ flag)
{
    const int lane = threadIdx.x & 63;
    const int row  = (blockIdx.x << 2) + (threadIdx.x >> 6);

    // encoding probe: byte-bool vs int32 0/1 (r2 analysis; r2-r8 verified)
    if (blockIdx.x == 0 && threadIdx.x < 64) {
        const int i = threadIdx.x + 1;
        const int ok = ((i & 3) != 0) && (adj[(size_t)i * (NN + 1)] != 0);
        unsigned long long bb = __ballot(ok);
        if (threadIdx.x == 0) *flag = (__popcll(bb) > 24) ? 1 : 0;
    }

    const float* xr = x + (size_t)row * DD;
    float x0 = xr[lane];
    float x1 = xr[lane + 64];

    float nsq = x0 * x0 + x1 * x1;
    #pragma unroll
    for (int o = 32; o > 0; o >>= 1) nsq += __shfl_xor(nsq, o);

    float norm = fmaxf(sqrtf(nsq), 1e-15f);
    float t    = fminf(norm, 1.0f - 1e-7f);
    float art  = 0.5f * (log1pf(t) - log1pf(-t));
    float scl  = art / norm;
    x0 *= scl;
    x1 *= scl;

    float hc[CLS];
    #pragma unroll
    for (int c = 0; c < CLS; ++c)
        hc[c] = x0 * W[lane * CLS + c] + x1 * W[(lane + 64) * CLS + c];

    #pragma unroll
    for (int o = 32; o > 0; o >>= 1) {
        #pragma unroll
        for (int c = 0; c < CLS; ++c) hc[c] += __shfl_xor(hc[c], o);
    }

    float sv = 0.0f, dvv = 0.0f;
    #pragma unroll
    for (int c = 0; c < CLS; ++c) {
        hc[c] += b[c];
        sv  += hc[c] * a_src[c];
        dvv += hc[c] * a_dst[c];
    }

    if (lane == 0) {
        float* hr = h + (size_t)row * CLS;
        #pragma unroll
        for (int c = 0; c < CLS; ++c) hr[c] = hc[c];
        s[row]  = sv;
        dv[row] = dvv;
    }
}

// ---------------------------------------------------------------------------
// Kernel 2: FUSED scan + softmax-aggregate. One block per row, 4 waves
// (quarter-rows, the r6 scan core — fastest measured). Hit indices are
// compacted into LDS (no global nbr round-trip, no extra launch), then
// processed in-wave: channel-split online softmax (group g=lane>>4 takes
// hit base+g, lane owns channel cc=lane&15), group merge via shfl_xor,
// wave merge via LDS, verified epilogue in wave 0.
// ---------------------------------------------------------------------------
__global__ __launch_bounds__(256) void hat_scan_agg(
    const unsigned char* __restrict__ adj, const int* __restrict__ flag,
    const float* __restrict__ h, const float* __restrict__ s,
    const float* __restrict__ dv, float* __restrict__ out)
{
    __shared__ int   nlist[4][QCAP];
    __shared__ float red[4][CLS + 2];

    const int lane = threadIdx.x & 63;
    const int q    = threadIdx.x >> 6;        // quarter 0..3
    const int row  = blockIdx.x;
    const bool bytemode = (*flag != 0);       // wave-uniform scalar

    // ---- scan quarter-row -> 32-bit hit mask per lane (r6-verified fold) ----
    unsigned mask = 0u;
    if (bytemode) {
        const uv4* abase = reinterpret_cast<const uv4*>(
            adj + (size_t)row * NN + q * 2048);
        #pragma unroll
        for (int it = 0; it < 2; ++it) {
            const uv4 a = abase[(it << 6) | lane];
            unsigned n0 = ((a[0] & 0x01010101u) * 0x01020408u) >> 24;
            unsigned n1 = ((a[1] & 0x01010101u) * 0x01020408u) >> 24;
            unsigned n2 = ((a[2] & 0x01010101u) * 0x01020408u) >> 24;
            unsigned n3 = ((a[3] & 0x01010101u) * 0x01020408u) >> 24;
            unsigned bits = (n0 & 0xF) | ((n1 & 0xF) << 4)
                          | ((n2 & 0xF) << 8) | ((n3 & 0xF) << 12);
            mask |= bits << (it << 4);
        }
    } else {
        const uv4* abase = reinterpret_cast<const uv4*>(
            reinterpret_cast<const unsigned int*>(adj) + (size_t)row * NN + q * 2048);
        #pragma unroll
        for (int it = 0; it < 8; ++it) {
            const uv4 a = abase[(it << 6) | lane];
            unsigned bits = (unsigned)(a[0] != 0u)        | ((unsigned)(a[1] != 0u) << 1)
                          | ((unsigned)(a[2] != 0u) << 2) | ((unsigned)(a[3] != 0u) << 3);
            mask |= bits << (it << 2);
        }
    }

    // ---- deterministic compaction into this wave's LDS segment ----
    const int c = __popc(mask);
    int off = c;
    #pragma unroll
    for (int o = 1; o < 64; o <<= 1) {
        int v = __shfl_up(off, o);
        if (lane >= o) off += v;
    }
    int total = __shfl(off, 63);
    off -= c;                                  // exclusive offset
    total = (total < QCAP) ? total : QCAP;

    while (mask) {
        const int b = __builtin_ctz(mask);
        mask &= mask - 1;
        const int j = bytemode
            ? (q * 2048 + ((b >> 4) << 10) + (lane << 4) + (b & 15))
            : (q * 2048 + ((b >> 2) << 8)  + (lane << 2) + (b & 3));
        if (off < QCAP) nlist[q][off] = j;
        ++off;
    }
    // (same wave wrote the segment -> in-wave LDS RAW, no block sync needed)

    // ---- channel-split online softmax over this quarter's hits ----
    const float si = s[row];
    const int cc = lane & 15;
    const int g  = lane >> 4;

    float m = -3.0e38f, l = 0.0f, acc = 0.0f;
    for (int base = 0; base < total; base += 4) {
        const int idx = base + g;
        if (idx < total) {
            const int j = nlist[q][idx];
            float e = si + dv[j];
            e = (e > 0.0f) ? e : ALPHA * e;               // LeakyReLU
            const float hv = h[(size_t)j * CLS + cc];     // 64B broadcast line
            if (e <= m) {                                  // common: 1 exp
                float w = __expf(e - m);
                l += w;
                acc = fmaf(w, hv, acc);
            } else {                                       // new max: rescale
                float sc = __expf(m - e);                  // exp(-inf)=0 first
                l   = fmaf(l, sc, 1.0f);
                acc = fmaf(acc, sc, hv);
                m = e;
            }
        }
    }

    // ---- merge the 4 groups within the wave (offsets 16, 32) ----
    #pragma unroll
    for (int o = 16; o <= 32; o <<= 1) {
        float mo = __shfl_xor(m, o);
        float lo = __shfl_xor(l, o);
        float ao = __shfl_xor(acc, o);
        float mn = fmaxf(m, mo);
        float sa = __expf(m - mn), sb = __expf(mo - mn);
        l   = l * sa + lo * sb;
        acc = acc * sa + ao * sb;
        m = mn;
    }

    // ---- merge the 4 waves via LDS; epilogue in wave 0 ----
    if (lane < CLS) red[q][2 + lane] = acc;
    if (lane == 0) { red[q][0] = m; red[q][1] = l; }
    __syncthreads();

    if (q == 0 && lane < CLS) {
        float M = red[0][0], L = red[0][1], A = red[0][2 + lane];
        #pragma unroll
        for (int w = 1; w < 4; ++w) {
            float mo = red[w][0], lo = red[w][1], ao = red[w][2 + lane];
            float mn = fmaxf(M, mo);
            float sa = __expf(M - mn), sb = __expf(mo - mn);
            L = L * sa + lo * sb;
            A = A * sa + ao * sb;
            M = mn;
        }
        float* orow = out + (size_t)row * CLS;
        if (L > 0.0f) {
            float u = A / L;
            u = (u > 0.0f) ? u : expm1f(u);               // elu
            float nsq = u * u;                            // 16-lane reduce
            #pragma unroll
            for (int o = 8; o > 0; o >>= 1) nsq += __shfl_xor(nsq, o);
            float norm = fmaxf(sqrtf(nsq), 1e-15f);
            float th   = tanhf(norm);
            float sc2  = th / norm;                        // expmap0 scale
            const float maxnorm = 1.0f - 1e-5f;            // proj (c=1)
            float sc3  = (th > maxnorm) ? (maxnorm / th) : 1.0f;
            orow[lane] = u * sc2 * sc3;
        } else {
            orow[lane] = 0.0f;
        }
    }
}

// ---------------------------------------------------------------------------
extern "C" void kernel_launch(void* const* d_in, const int* in_sizes, int n_in,
                              void* d_out, int out_size, void* d_ws, size_t ws_size,
                              hipStream_t stream) {
    const float*         x     = (const float*)d_in[0];
    const unsigned char* adj   = (const unsigned char*)d_in[1];
    const float*         W     = (const float*)d_in[2];
    const float*         b     = (const float*)d_in[3];
    const float*         a_src = (const float*)d_in[4];
    const float*         a_dst = (const float*)d_in[5];
    float*               out   = (float*)d_out;

    float* h    = (float*)d_ws;                    // [NN, CLS]
    float* s    = h + (size_t)NN * CLS;            // [NN]
    float* dv   = s + NN;                          // [NN]
    int*   flag = (int*)(dv + NN);                 // [1]

    hat_feat    <<<NN / 4, 256, 0, stream>>>(x, W, b, a_src, a_dst, adj,
                                             h, s, dv, flag);
    hat_scan_agg<<<NN,     256, 0, stream>>>(adj, flag, h, s, dv, out);
}